// Round 9
// baseline (191.193 us; speedup 1.0000x reference)
//
#include <hip/hip_runtime.h>
#include <hip/hip_bf16.h>

#define B_   32
#define L_   1024
#define DIN  256

typedef __bf16 bf16x8 __attribute__((ext_vector_type(8)));
typedef float  f32x4  __attribute__((ext_vector_type(4)));
typedef unsigned short u16;

union U8 { u16 s[8]; bf16x8 v; };
union VU { uint2 p[2]; bf16x8 v; };

__device__ __forceinline__ u16 f2b(float f) {
  union { float f; unsigned u; } v; v.f = f;
  unsigned r = (v.u + 0x7FFFu + ((v.u >> 16) & 1u)) >> 16;
  return (u16)r;
}
__device__ __forceinline__ float b2f(u16 h) {
  union { unsigned u; float f; } c; c.u = ((unsigned)h) << 16;
  return c.f;
}

// HW transpose-read: lane fetches 8B at its addr; 16-lane group spans 128B =
// 4 rows x 16 bf16; lane l receives column (l&15) of those 4 rows.
#define TR16_0(dst, addr) \
  asm volatile("ds_read_b64_tr_b16 %0, %1 offset:0" : "=&v"(dst) : "v"(addr))
#define TR16_128(dst, addr) \
  asm volatile("ds_read_b64_tr_b16 %0, %1 offset:128" : "=&v"(dst) : "v"(addr))

// ---------------------------------------------------------------------------
// k_fold, grid 273:
//  blocks [0,128):   Wc^T = (W_eg@Wg)^T -> WbT rows 128..255 (Wg staged in LDS)
//  blocks [128,256): W_ge^T -> WbT rows 0..127
//  blocks [256,273): bc = b_eg@Wg ; TT zeroed
// ---------------------------------------------------------------------------
__global__ __launch_bounds__(256) void k_fold(
    const float* __restrict__ W_ge, const float* __restrict__ b_eg,
    const float* __restrict__ W_eg, const float* __restrict__ Wg,
    u16* __restrict__ WbT, float* __restrict__ bc, float* __restrict__ TT) {
  __shared__ float WgL[128 * 128];
  const int blk = blockIdx.x, tid = threadIdx.x;
  if (blk < 128) {
    // stage Wg (64KB) coalesced
    const float4* src = (const float4*)Wg;
    float4* dst = (float4*)WgL;
#pragma unroll
    for (int i = 0; i < 16; ++i) dst[tid + i * 256] = src[tid + i * 256];
    __syncthreads();
    const int d = blk * 2 + (tid >> 7);    // wave-uniform
    const int o = tid & 127;
    const float* we = &W_eg[d * 128];      // scalar-cached reads
    float s = 0.f;
#pragma unroll 8
    for (int k = 0; k < 128; ++k) s += we[k] * WgL[k * 128 + o];
    WbT[(128 + o) * 256 + d] = f2b(s);
  } else if (blk < 256) {
    int i = (blk - 128) * 256 + tid;       // 0..32767
    int d = i >> 7, o = i & 127;
    WbT[o * 256 + d] = f2b(W_ge[d * 128 + o]);
  } else {
    int i = (blk - 256) * 256 + tid;       // 0..4351
    if (i < 128) {
      float s = 0.f;
      for (int k = 0; k < 128; ++k) s += b_eg[k] * Wg[k * 128 + i];
      bc[i] = s;
    } else if (i < 128 + 4096) {
      TT[i - 128] = 0.f;                   // zero TT (ws is poisoned)
    }
  }
}

// ---------------------------------------------------------------------------
// k_embed: [EA|TH](bf16) = traj @ [W_ge|Wc] + bias via MFMA, tail sums fused.
// 512 blocks x 256 threads (4 waves), 64 traj rows per block.
// Weight A-fragments read DIRECTLY from global WbT (131KB, L2-resident) --
// no LDS staging, no compute barriers. EA half skipped for blocks fully
// beyond len. Tail: Sum_{row>=len} TH -> TT.
// ---------------------------------------------------------------------------
__global__ __launch_bounds__(256) void k_embed(
    const float* __restrict__ traj, const u16* __restrict__ WbT,
    const float* __restrict__ b_ge, const float* __restrict__ bc,
    const int* __restrict__ lens,
    u16* __restrict__ EA, u16* __restrict__ TH, float* __restrict__ TT) {
  __shared__ float tailLds[128];
  const int tid = threadIdx.x;
  const int wv = tid >> 6, ln = tid & 63;
  const int li = ln & 15, g = ln >> 4;
  const int b   = blockIdx.x >> 4;             // 16 blocks per batch
  const int rl0 = (blockIdx.x & 15) * 64;
  const int len = lens[b];
  const int rw  = rl0 + wv * 16 + li;          // row within batch
  const size_t row = (size_t)b * L_ + rw;
  const int nd0 = (rl0 >= len) ? 8 : 0;        // skip EA for fully-masked blk
  const bool doTail = (rl0 + 64 > len);

  if (tid < 128) tailLds[tid] = 0.f;
  __syncthreads();

  f32x4 acc[16] = {};
  const float* tp = &traj[row * DIN];

  for (int kc = 0; kc < 8; ++kc) {
    // traj B-fragment for this k-chunk (f32 -> bf16)
    float4 v0 = *(const float4*)(tp + kc * 32 + g * 8);
    float4 v1 = *(const float4*)(tp + kc * 32 + g * 8 + 4);
    U8 bu;
    bu.s[0]=f2b(v0.x); bu.s[1]=f2b(v0.y); bu.s[2]=f2b(v0.z); bu.s[3]=f2b(v0.w);
    bu.s[4]=f2b(v1.x); bu.s[5]=f2b(v1.y); bu.s[6]=f2b(v1.z); bu.s[7]=f2b(v1.w);
#pragma unroll
    for (int nd = 0; nd < 16; ++nd) {
      if (nd >= nd0) {
        bf16x8 afrag = *(const bf16x8*)&WbT[(nd * 16 + li) * 256 + kc * 32 + g * 8];
        acc[nd] = __builtin_amdgcn_mfma_f32_16x16x32_bf16(afrag, bu.v, acc[nd], 0, 0, 0);
      }
    }
  }

#pragma unroll
  for (int nd = 0; nd < 16; ++nd) {
    if (nd < nd0) continue;
    int ncol = nd * 16 + 4 * g;
    float fv[4];
    u16 pk[4];
#pragma unroll
    for (int r = 0; r < 4; ++r) {
      int n = ncol + r;
      float bias = (n < 128) ? b_ge[n] : bc[n - 128];
      fv[r] = acc[nd][r] + bias;
      pk[r] = f2b(fv[r]);
    }
    u16* dst = (ncol < 128) ? &EA[row * 128 + ncol]
                            : &TH[row * 128 + (ncol - 128)];
    *(uint2*)dst = *(uint2*)pk;

    if (nd >= 8 && doTail) {               // tail contribution (uniform branch)
      float tv[4];
#pragma unroll
      for (int r = 0; r < 4; ++r) tv[r] = (rw >= len) ? fv[r] : 0.f;
#pragma unroll
      for (int d = 1; d < 16; d <<= 1)
#pragma unroll
        for (int r = 0; r < 4; ++r) tv[r] += __shfl_xor(tv[r], d, 16);
      if (li == 0) {
#pragma unroll
        for (int r = 0; r < 4; ++r)
          atomicAdd(&tailLds[(nd - 8) * 16 + 4 * g + r], tv[r]);
      }
    }
  }
  __syncthreads();
  if (tid < 128) {
    float v = tailLds[tid];
    if (v != 0.f) atomicAdd(&TT[b * 128 + tid], v);
  }
}

// ---------------------------------------------------------------------------
// k_attn: flash attention + masked-column tail + layernorm + row mask.
// (unchanged from the round-8 PASS)
// ---------------------------------------------------------------------------
#define PSTR 40

__global__ __launch_bounds__(256) void k_attn(
    const u16* __restrict__ EA, const u16* __restrict__ TH,
    const float* __restrict__ TT, const int* __restrict__ lens,
    const float* __restrict__ gamma, const float* __restrict__ beta,
    float* __restrict__ out) {
  const int b  = blockIdx.y;
  const int i0 = blockIdx.x * 32;
  const int len = lens[b];
  const int tid = threadIdx.x;
  const size_t obase = ((size_t)b * L_ + i0) * 128;

  if (i0 >= len) {                         // fully masked tile -> zeros
    float4 z = {0.f, 0.f, 0.f, 0.f};
    for (int q = tid; q < 1024; q += 256) *(float4*)&out[obase + (size_t)q * 4] = z;
    return;
  }

  __shared__ u16 Kl[2][2][4096];           // [p][buf][swizzled 32x128]
  __shared__ u16 Vl[2][2][4096];           // [p][buf][t8*512 + j*16 + d%16]
  __shared__ u16 Pl[4][640];               // per-wave P tile (PSTR=40)
  __shared__ float MLm[32], MLl[32];
  __shared__ u16 MGb[32][136];             // p=1 O partials (bf16)

  const int wv = tid >> 6;
  const int h = wv & 1, p = wv >> 1;
  const int ln = tid & 63, li = ln & 15, g = ln >> 4;
  const int ptid = tid & 127;              // waves {2p,2p+1} contiguous
  const int jr = ptid >> 2, ch = ptid & 3;
  const size_t ebase = (size_t)b * L_ * 128;

  u16* pl = Pl[wv];

  // Q fragments (rows i0 + h*16 + li), hoisted
  bf16x8 qf[4];
  {
    const u16* qp = &EA[ebase + (size_t)(i0 + h * 16 + li) * 128 + g * 8];
#pragma unroll
    for (int kc = 0; kc < 4; ++kc) qf[kc] = *(const bf16x8*)&qp[kc * 32];
  }

  f32x4 Oa[8] = {};
  float m[4] = {0.f, 0.f, 0.f, 0.f};
  float lsum[4] = {0.f, 0.f, 0.f, 0.f};

  const int njt = (len + 31) >> 5;
  const int kiter = (njt + 1) >> 1;

  // prologue: issue loads for this parity's first tile
  bf16x8 kreg[4], vreg[4];
  {
    const int t0 = (p < njt) ? p : (njt - 1);
    const u16* ks = &EA[ebase + (size_t)(t0 * 32 + jr) * 128];
    const u16* vs = &TH[ebase + (size_t)(t0 * 32 + jr) * 128];
#pragma unroll
    for (int k = 0; k < 4; ++k) {
      kreg[k] = *(const bf16x8*)(ks + (ch + 4 * k) * 8);
      vreg[k] = *(const bf16x8*)(vs + (ch + 4 * k) * 8);
    }
  }

  for (int kk = 0; kk < kiter; ++kk) {
    const int t = 2 * kk + p;
    u16* kd = Kl[p][kk & 1];
    u16* vd = Vl[p][kk & 1];
    // write staged regs to LDS (b128 only)
#pragma unroll
    for (int k = 0; k < 4; ++k) {
      int cq = ch + 4 * k;
      int cb = cq * 16;
      *(bf16x8*)((char*)kd + jr * 256 + (cb ^ ((jr & 7) << 4))) = kreg[k];
      *(bf16x8*)&vd[(cq >> 1) * 512 + jr * 16 + (cq & 1) * 8] = vreg[k];
    }
    // issue next tile's loads (land during this tile's compute)
    if (kk + 1 < kiter) {
      int tn = 2 * (kk + 1) + p; if (tn > njt - 1) tn = njt - 1;
      const u16* ks = &EA[ebase + (size_t)(tn * 32 + jr) * 128];
      const u16* vs = &TH[ebase + (size_t)(tn * 32 + jr) * 128];
#pragma unroll
      for (int k = 0; k < 4; ++k) {
        kreg[k] = *(const bf16x8*)(ks + (ch + 4 * k) * 8);
        vreg[k] = *(const bf16x8*)(vs + (ch + 4 * k) * 8);
      }
    }
    __syncthreads();
    if (t < njt) {
      const int j0 = t * 32;
      // QK^T
      f32x4 S[2] = {};
#pragma unroll
      for (int n = 0; n < 2; ++n) {
        int krow = n * 16 + li;
        const char* kb = (const char*)kd + krow * 256;
#pragma unroll
        for (int kc = 0; kc < 4; ++kc) {
          bf16x8 kf = *(const bf16x8*)(kb + ((kc * 64 + g * 16) ^ ((krow & 7) << 4)));
          S[n] = __builtin_amdgcn_mfma_f32_16x16x32_bf16(qf[kc], kf, S[n], 0, 0, 0);
        }
      }
      // V transpose-reads (overlap with softmax VALU)
      const unsigned vtr = (unsigned)(size_t)vd + g * 256 + li * 8;
      uint2 vr[16];
#pragma unroll
      for (int t8 = 0; t8 < 8; ++t8) {
        unsigned a = vtr + t8 * 1024;
        TR16_0(vr[2 * t8], a);
        TR16_128(vr[2 * t8 + 1], a);
      }
      // relu + in-tile mask + online softmax
      const bool v0 = (j0 + li) < len;
      const bool v1 = (j0 + 16 + li) < len;
      float x[4];
#pragma unroll
      for (int r = 0; r < 4; ++r) {
        float s0 = v0 ? fmaxf(S[0][r], 0.f) : 0.f;
        float s1 = v1 ? fmaxf(S[1][r], 0.f) : 0.f;
        S[0][r] = s0; S[1][r] = s1;
        x[r] = fmaxf(s0, s1);
      }
#pragma unroll
      for (int d = 1; d < 16; d <<= 1)
#pragma unroll
        for (int r = 0; r < 4; ++r) x[r] = fmaxf(x[r], __shfl_xor(x[r], d, 16));

      float p0[4], p1[4], fac[4], y[4];
#pragma unroll
      for (int r = 0; r < 4; ++r) {
        float mt = fmaxf(m[r], x[r]);
        fac[r] = __expf(m[r] - mt);
        m[r] = mt;
        p0[r] = v0 ? __expf(S[0][r] - mt) : 0.f;
        p1[r] = v1 ? __expf(S[1][r] - mt) : 0.f;
        y[r] = p0[r] + p1[r];
      }
#pragma unroll
      for (int d = 1; d < 16; d <<= 1)
#pragma unroll
        for (int r = 0; r < 4; ++r) y[r] += __shfl_xor(y[r], d, 16);
#pragma unroll
      for (int r = 0; r < 4; ++r) lsum[r] = lsum[r] * fac[r] + y[r];
#pragma unroll
      for (int t8 = 0; t8 < 8; ++t8)
#pragma unroll
        for (int r = 0; r < 4; ++r) Oa[t8][r] *= fac[r];

      // P -> per-wave LDS, read back as A-fragment
#pragma unroll
      for (int r = 0; r < 4; ++r) {
        pl[(4 * g + r) * PSTR + li]      = f2b(p0[r]);
        pl[(4 * g + r) * PSTR + 16 + li] = f2b(p1[r]);
      }
      bf16x8 pf = *(const bf16x8*)&pl[li * PSTR + g * 8];

      asm volatile("s_waitcnt lgkmcnt(0)" ::: "memory");
      __builtin_amdgcn_sched_barrier(0);

#pragma unroll
      for (int t8 = 0; t8 < 8; ++t8) {
        VU vu; vu.p[0] = vr[2 * t8]; vu.p[1] = vr[2 * t8 + 1];
        Oa[t8] = __builtin_amdgcn_mfma_f32_16x16x32_bf16(pf, vu.v, Oa[t8], 0, 0, 0);
      }
    }
  }

  // ---- merge parity partials ----
  __syncthreads();
  if (p == 1) {
#pragma unroll
    for (int r = 0; r < 4; ++r) {
      int rr = h * 16 + 4 * g + r;
      if (li == 0) { MLm[rr] = m[r]; MLl[rr] = lsum[r]; }
#pragma unroll
      for (int t8 = 0; t8 < 8; ++t8)
        MGb[rr][t8 * 16 + li] = f2b(Oa[t8][r]);
    }
  }
  __syncthreads();
  if (p != 0) return;

#pragma unroll
  for (int r = 0; r < 4; ++r) {
    int rr = h * 16 + 4 * g + r;
    float m1 = MLm[rr], l1 = MLl[rr];
    float ms = fmaxf(m[r], m1);
    float f0 = __expf(m[r] - ms), f1 = __expf(m1 - ms);
    lsum[r] = lsum[r] * f0 + l1 * f1;
    m[r] = ms;
#pragma unroll
    for (int t8 = 0; t8 < 8; ++t8)
      Oa[t8][r] = Oa[t8][r] * f0 + b2f(MGb[rr][t8 * 16 + li]) * f1;
  }

  // masked-column tail: (L-len) cols with score 0 -> weight e^{-m}
  {
    float tt8[8];
#pragma unroll
    for (int t8 = 0; t8 < 8; ++t8) tt8[t8] = TT[b * 128 + t8 * 16 + li];
#pragma unroll
    for (int r = 0; r < 4; ++r) {
      float wt = __expf(-m[r]);
      lsum[r] += wt * (float)(L_ - len);
#pragma unroll
      for (int t8 = 0; t8 < 8; ++t8) Oa[t8][r] += wt * tt8[t8];
    }
  }

  // normalize + layernorm
  float sm[4] = {0.f, 0.f, 0.f, 0.f}, sq[4] = {0.f, 0.f, 0.f, 0.f};
#pragma unroll
  for (int r = 0; r < 4; ++r) {
    float inv = 1.f / lsum[r];
#pragma unroll
    for (int t8 = 0; t8 < 8; ++t8) {
      float val = Oa[t8][r] * inv;
      Oa[t8][r] = val;
      sm[r] += val; sq[r] += val * val;
    }
  }
#pragma unroll
  for (int d = 1; d < 16; d <<= 1)
#pragma unroll
    for (int r = 0; r < 4; ++r) {
      sm[r] += __shfl_xor(sm[r], d, 16);
      sq[r] += __shfl_xor(sq[r], d, 16);
    }

  const int irow = i0 + h * 16;
#pragma unroll
  for (int r = 0; r < 4; ++r) {
    float mu   = sm[r] * (1.f / 128.f);
    float var  = sq[r] * (1.f / 128.f) - mu * mu;
    float rstd = rsqrtf(var + 1e-5f);
    int i = irow + 4 * g + r;
    bool valid = i < len;
#pragma unroll
    for (int t8 = 0; t8 < 8; ++t8) {
      int dcol = t8 * 16 + li;
      float o = valid ? ((Oa[t8][r] - mu) * rstd * gamma[dcol] + beta[dcol]) : 0.f;
      out[((size_t)b * L_ + i) * 128 + dcol] = o;
    }
  }
}

// ---------------------------------------------------------------------------
extern "C" void kernel_launch(void* const* d_in, const int* in_sizes, int n_in,
                              void* d_out, int out_size, void* d_ws, size_t ws_size,
                              hipStream_t stream) {
  const float* traj  = (const float*)d_in[0];
  const int*   lens  = (const int*)d_in[1];
  const float* W_ge  = (const float*)d_in[2];
  const float* b_ge  = (const float*)d_in[3];
  const float* W_eg  = (const float*)d_in[4];
  const float* b_eg  = (const float*)d_in[5];
  const float* Wg    = (const float*)d_in[6];
  const float* gamma = (const float*)d_in[7];
  const float* beta  = (const float*)d_in[8];
  float* out = (float*)d_out;

  // workspace: WbT bf16[256*256] | bc f32[128] | TT f32[32*128] | EA bf16 | TH bf16
  char* ws = (char*)d_ws;
  u16*   WbT = (u16*)ws;
  float* bc  = (float*)(ws + 131072);
  float* TT  = (float*)(ws + 131072 + 512);
  u16*   EA  = (u16*)(ws + 131072 + 512 + 16384);
  u16*   TH  = EA + (size_t)B_ * L_ * 128;

  k_fold<<<273, 256, 0, stream>>>(W_ge, b_eg, W_eg, Wg, WbT, bc, TT);
  k_embed<<<512, 256, 0, stream>>>(traj, WbT, b_ge, bc, lens, EA, TH, TT);
  k_attn<<<dim3(32, 32), 256, 0, stream>>>(EA, TH, TT, lens, gamma, beta, out);
}